// Round 1
// baseline (516.129 us; speedup 1.0000x reference)
//
#include <hip/hip_runtime.h>
#include <hip/hip_bf16.h>

#define B_ 2
#define S_ 2048
#define D_ 1024
#define H_ 16
#define HD_ 64

typedef short bf16x8 __attribute__((ext_vector_type(8)));
typedef float f32x4 __attribute__((ext_vector_type(4)));

__device__ __forceinline__ f32x4 mfma16(bf16x8 a, bf16x8 b, f32x4 c) {
    return __builtin_amdgcn_mfma_f32_16x16x32_bf16(a, b, c, 0, 0, 0);
}

__device__ __forceinline__ bf16x8 ldb8(const __hip_bfloat16* p) {
    return *reinterpret_cast<const bf16x8*>(p);
}

// ---------------- fp32 -> bf16 conversion ----------------
__global__ __launch_bounds__(256) void conv_kernel(const float* __restrict__ src,
                                                   __hip_bfloat16* __restrict__ dst, int n4) {
    int i = blockIdx.x * 256 + threadIdx.x;
    if (i >= n4) return;
    float4 f = reinterpret_cast<const float4*>(src)[i];
    union { __hip_bfloat16 h[4]; ushort4 u; } cv;
    cv.h[0] = __float2bfloat16(f.x);
    cv.h[1] = __float2bfloat16(f.y);
    cv.h[2] = __float2bfloat16(f.z);
    cv.h[3] = __float2bfloat16(f.w);
    reinterpret_cast<ushort4*>(dst)[i] = cv.u;
}

// ---------------- GEMM: Y = X @ W^T + bias ----------------
// X: [M][K] bf16 row-major, W: [N][K] bf16 row-major (so both operands read
// 8 contiguous K-elements per lane -> natural MFMA fragments).
// MODE 0: fused QKV. N = 3072 (Wq|Wk|Wv rows stacked). Writes:
//   n in [0,1024)   -> Qh[b][h][s][hd] bf16
//   n in [1024,2048)-> Kh[b][h][s][hd] bf16
//   n in [2048,3072)-> Vt[b][h][hd][s] bf16   (transposed for PV B-fragments)
// MODE 1: out-projection, writes fp32 Y[m][n] = v + bias0[n].
template <int MODE>
__global__ __launch_bounds__(256) void gemm_bt(
    const __hip_bfloat16* __restrict__ X, const __hip_bfloat16* __restrict__ Wt,
    const float* __restrict__ bias0, const float* __restrict__ bias1,
    const float* __restrict__ bias2,
    __hip_bfloat16* __restrict__ Yq, __hip_bfloat16* __restrict__ Yk,
    __hip_bfloat16* __restrict__ Yv, float* __restrict__ Yo,
    int M, int N, int K) {
    // padded stride 40 elems = 80 B: 16B-aligned, conflict-free-ish (2-way max)
    __shared__ __hip_bfloat16 As[128][40];
    __shared__ __hip_bfloat16 Bs[128][40];

    const int ntn = N >> 7;
    const int tm = blockIdx.x / ntn;
    const int tn = blockIdx.x % ntn;
    const int t = threadIdx.x;
    const int w = t >> 6, l = t & 63, g = l >> 4, c = l & 15;
    const int wr = w >> 1, wc = w & 1;

    const int arow = t >> 1;            // 0..127
    const int acol0 = (t & 1) * 16;     // 0 or 16

    const size_t xrow = (size_t)(tm * 128 + arow) * K;
    const size_t wrow = (size_t)(tn * 128 + arow) * K;

    f32x4 acc[4][4] = {};

    for (int k0 = 0; k0 < K; k0 += 32) {
        __syncthreads();  // protect previous iteration's LDS reads
        *reinterpret_cast<bf16x8*>(&As[arow][acol0])     = ldb8(&X[xrow + k0 + acol0]);
        *reinterpret_cast<bf16x8*>(&As[arow][acol0 + 8]) = ldb8(&X[xrow + k0 + acol0 + 8]);
        *reinterpret_cast<bf16x8*>(&Bs[arow][acol0])     = ldb8(&Wt[wrow + k0 + acol0]);
        *reinterpret_cast<bf16x8*>(&Bs[arow][acol0 + 8]) = ldb8(&Wt[wrow + k0 + acol0 + 8]);
        __syncthreads();

        bf16x8 am[4], bn[4];
#pragma unroll
        for (int mi = 0; mi < 4; ++mi) am[mi] = ldb8(&As[wr * 64 + mi * 16 + c][g * 8]);
#pragma unroll
        for (int ni = 0; ni < 4; ++ni) bn[ni] = ldb8(&Bs[wc * 64 + ni * 16 + c][g * 8]);
#pragma unroll
        for (int mi = 0; mi < 4; ++mi)
#pragma unroll
            for (int ni = 0; ni < 4; ++ni)
                acc[mi][ni] = mfma16(am[mi], bn[ni], acc[mi][ni]);
    }

    // epilogue: C/D layout col = lane&15, row = (lane>>4)*4 + r  [m89-verified]
#pragma unroll
    for (int mi = 0; mi < 4; ++mi) {
        const int mbase = tm * 128 + wr * 64 + mi * 16 + g * 4;
#pragma unroll
        for (int ni = 0; ni < 4; ++ni) {
            const int n = tn * 128 + wc * 64 + ni * 16 + c;
#pragma unroll
            for (int r = 0; r < 4; ++r) {
                const int mm = mbase + r;
                float v = acc[mi][ni][r];
                if (MODE == 0) {
                    const float* bp = (n < 1024) ? bias0 : (n < 2048) ? bias1 : bias2;
                    const int nn = n & 1023;
                    v += bp[nn];
                    const int b = mm >> 11, s = mm & 2047;
                    const int h = nn >> 6, hd = nn & 63;
                    const size_t bh = (size_t)(b * H_ + h);
                    const __hip_bfloat16 bvv = __float2bfloat16(v);
                    if (n < 2048) {
                        __hip_bfloat16* dst = (n < 1024) ? Yq : Yk;
                        dst[(bh * S_ + s) * HD_ + hd] = bvv;
                    } else {
                        Yv[(bh * HD_ + hd) * S_ + s] = bvv;
                    }
                } else {
                    Yo[(size_t)mm * N + n] = v + bias0[n];
                }
            }
        }
    }
}

// ---------------- fused attention: scores -> softmax -> probs(out) + PV ----------------
// grid: B*H*(S/64) blocks, 4 waves; wave owns 16 q-rows.
// pass 1: row sums of exp(score) (no max subtraction: scores bounded ~|8|, fp32 safe)
// pass 2: p = exp(score)/sum -> write fp32 probs, stage bf16 P in LDS, PV MFMA.
__global__ __launch_bounds__(256) void attn_kernel(
    const __hip_bfloat16* __restrict__ Qh, const __hip_bfloat16* __restrict__ Kh,
    const __hip_bfloat16* __restrict__ Vt, const float* __restrict__ mask,
    float* __restrict__ probs, __hip_bfloat16* __restrict__ ctx) {
    __shared__ __hip_bfloat16 Pst[4][16][40];  // per-wave P stage, 2-way-conflict-free

    const int blk = blockIdx.x;
    const int qt = blk & 31;
    const int bh = blk >> 5;
    const int b = bh >> 4, h = bh & 15;
    const int w = threadIdx.x >> 6, l = threadIdx.x & 63, g = l >> 4, c = l & 15;
    const int q0 = qt * 64 + w * 16;

    const __hip_bfloat16* Qb = Qh + (size_t)bh * S_ * HD_;
    const __hip_bfloat16* Kb = Kh + (size_t)bh * S_ * HD_;
    const __hip_bfloat16* Vb = Vt + (size_t)bh * HD_ * S_;
    const float* mrow = mask + (size_t)b * S_;

    const bf16x8 aq0 = ldb8(&Qb[(q0 + c) * HD_ + g * 8]);
    const bf16x8 aq1 = ldb8(&Qb[(q0 + c) * HD_ + 32 + g * 8]);

    // ---- pass 1: denominator ----
    float lsum[4] = {0.f, 0.f, 0.f, 0.f};
    for (int kt = 0; kt < S_ / 16; ++kt) {
        const bf16x8 bk0 = ldb8(&Kb[(kt * 16 + c) * HD_ + g * 8]);
        const bf16x8 bk1 = ldb8(&Kb[(kt * 16 + c) * HD_ + 32 + g * 8]);
        f32x4 acc = {0.f, 0.f, 0.f, 0.f};
        acc = mfma16(aq0, bk0, acc);
        acc = mfma16(aq1, bk1, acc);
        const float mk = mrow[kt * 16 + c];
#pragma unroll
        for (int r = 0; r < 4; ++r) lsum[r] += __expf(acc[r] * 0.125f + mk);
    }
#pragma unroll
    for (int r = 0; r < 4; ++r) {
#pragma unroll
        for (int msk = 1; msk < 16; msk <<= 1) lsum[r] += __shfl_xor(lsum[r], msk);
    }
    float inv[4];
#pragma unroll
    for (int r = 0; r < 4; ++r) inv[r] = 1.0f / lsum[r];

    // ---- pass 2: probs write + PV ----
    f32x4 cacc[4] = {};
    float* prow = probs + ((size_t)bh * S_ + q0 + g * 4) * S_ + c;
    for (int ktp = 0; ktp < S_ / 32; ++ktp) {
#pragma unroll
        for (int sub = 0; sub < 2; ++sub) {
            const int kt = ktp * 2 + sub;
            const bf16x8 bk0 = ldb8(&Kb[(kt * 16 + c) * HD_ + g * 8]);
            const bf16x8 bk1 = ldb8(&Kb[(kt * 16 + c) * HD_ + 32 + g * 8]);
            f32x4 acc = {0.f, 0.f, 0.f, 0.f};
            acc = mfma16(aq0, bk0, acc);
            acc = mfma16(aq1, bk1, acc);
            const float mk = mrow[kt * 16 + c];
#pragma unroll
            for (int r = 0; r < 4; ++r) {
                const float p = __expf(acc[r] * 0.125f + mk) * inv[r];
                prow[(size_t)r * S_ + kt * 16] = p;
                Pst[w][g * 4 + r][sub * 16 + c] = __float2bfloat16(p);
            }
        }
        asm volatile("s_waitcnt lgkmcnt(0)" ::: "memory");
        const bf16x8 ap = ldb8(&Pst[w][c][g * 8]);
        const int k0 = ktp * 32;
#pragma unroll
        for (int n = 0; n < 4; ++n) {
            const bf16x8 bv = ldb8(&Vb[(n * 16 + c) * S_ + k0 + g * 8]);
            cacc[n] = mfma16(ap, bv, cacc[n]);
        }
    }

    __hip_bfloat16* crow = ctx + ((size_t)b * S_ + q0 + g * 4) * D_ + h * HD_ + c;
#pragma unroll
    for (int n = 0; n < 4; ++n)
#pragma unroll
        for (int r = 0; r < 4; ++r)
            crow[(size_t)r * D_ + n * 16] = __float2bfloat16(cacc[n][r]);
}

// ---------------- launch ----------------
extern "C" void kernel_launch(void* const* d_in, const int* in_sizes, int n_in,
                              void* d_out, int out_size, void* d_ws, size_t ws_size,
                              hipStream_t stream) {
    const float* hs   = (const float*)d_in[0];
    const float* mask = (const float*)d_in[1];
    const float* Wq   = (const float*)d_in[2];
    const float* bq   = (const float*)d_in[3];
    const float* Wk   = (const float*)d_in[4];
    const float* bk   = (const float*)d_in[5];
    const float* Wv   = (const float*)d_in[6];
    const float* bv   = (const float*)d_in[7];
    const float* Wo   = (const float*)d_in[8];
    const float* bo   = (const float*)d_in[9];

    float* out   = (float*)d_out;
    float* probs = out + (size_t)B_ * S_ * D_;

    const size_t MD = (size_t)B_ * S_ * D_;  // 4096*1024
    __hip_bfloat16* hsb   = (__hip_bfloat16*)d_ws;
    __hip_bfloat16* wqkvb = hsb + MD;
    __hip_bfloat16* wob   = wqkvb + 3u * 1024u * 1024u;
    __hip_bfloat16* Qh    = wob + (size_t)1024 * 1024;
    __hip_bfloat16* Kh    = Qh + MD;
    __hip_bfloat16* Vt    = Kh + MD;
    __hip_bfloat16* ctxb  = Vt + MD;

    conv_kernel<<<4096, 256, 0, stream>>>(hs, hsb, (int)(MD / 4));
    conv_kernel<<<1024, 256, 0, stream>>>(Wq, wqkvb, 262144);
    conv_kernel<<<1024, 256, 0, stream>>>(Wk, wqkvb + 1048576, 262144);
    conv_kernel<<<1024, 256, 0, stream>>>(Wv, wqkvb + 2097152, 262144);
    conv_kernel<<<1024, 256, 0, stream>>>(Wo, wob, 262144);

    gemm_bt<0><<<32 * 24, 256, 0, stream>>>(hsb, wqkvb, bq, bk, bv,
                                            Qh, Kh, Vt, nullptr, 4096, 3072, 1024);

    attn_kernel<<<B_ * H_ * (S_ / 64), 256, 0, stream>>>(Qh, Kh, Vt, mask, probs, ctxb);

    gemm_bt<1><<<32 * 8, 256, 0, stream>>>(ctxb, wob, bo, nullptr, nullptr,
                                           nullptr, nullptr, nullptr, out, 4096, 1024, 1024);
}

// Round 2
// 480.545 us; speedup vs baseline: 1.0740x; 1.0740x over previous
//
#include <hip/hip_runtime.h>
#include <hip/hip_bf16.h>

#define B_ 2
#define S_ 2048
#define D_ 1024
#define H_ 16
#define HD_ 64

typedef short bf16x8 __attribute__((ext_vector_type(8)));
typedef short bf16x4 __attribute__((ext_vector_type(4)));
typedef float f32x4 __attribute__((ext_vector_type(4)));

__device__ __forceinline__ f32x4 mfma16(bf16x8 a, bf16x8 b, f32x4 c) {
    return __builtin_amdgcn_mfma_f32_16x16x32_bf16(a, b, c, 0, 0, 0);
}

__device__ __forceinline__ bf16x8 ldb8(const __hip_bfloat16* p) {
    return *reinterpret_cast<const bf16x8*>(p);
}

__device__ __forceinline__ float bf2f(short u) {
    union { unsigned int i; float f; } cv;
    cv.i = ((unsigned int)(unsigned short)u) << 16;
    return cv.f;
}

// ---------------- fp32 -> bf16 conversion ----------------
__global__ __launch_bounds__(256) void conv_kernel(const float* __restrict__ src,
                                                   __hip_bfloat16* __restrict__ dst, int n4) {
    int i = blockIdx.x * 256 + threadIdx.x;
    if (i >= n4) return;
    float4 f = reinterpret_cast<const float4*>(src)[i];
    union { __hip_bfloat16 h[4]; ushort4 u; } cv;
    cv.h[0] = __float2bfloat16(f.x);
    cv.h[1] = __float2bfloat16(f.y);
    cv.h[2] = __float2bfloat16(f.z);
    cv.h[3] = __float2bfloat16(f.w);
    reinterpret_cast<ushort4*>(dst)[i] = cv.u;
}

// ---------------- GEMM: Y = X @ W^T + bias ----------------
template <int MODE>
__global__ __launch_bounds__(256) void gemm_bt(
    const __hip_bfloat16* __restrict__ X, const __hip_bfloat16* __restrict__ Wt,
    const float* __restrict__ bias0, const float* __restrict__ bias1,
    const float* __restrict__ bias2,
    __hip_bfloat16* __restrict__ Yq, __hip_bfloat16* __restrict__ Yk,
    __hip_bfloat16* __restrict__ Yv, float* __restrict__ Yo,
    int M, int N, int K) {
    __shared__ __hip_bfloat16 As[128][40];
    __shared__ __hip_bfloat16 Bs[128][40];

    const int ntn = N >> 7;
    const int tm = blockIdx.x / ntn;
    const int tn = blockIdx.x % ntn;
    const int t = threadIdx.x;
    const int w = t >> 6, l = t & 63, g = l >> 4, c = l & 15;
    const int wr = w >> 1, wc = w & 1;

    const int arow = t >> 1;
    const int acol0 = (t & 1) * 16;

    const size_t xrow = (size_t)(tm * 128 + arow) * K;
    const size_t wrow = (size_t)(tn * 128 + arow) * K;

    f32x4 acc[4][4] = {};

    for (int k0 = 0; k0 < K; k0 += 32) {
        __syncthreads();
        *reinterpret_cast<bf16x8*>(&As[arow][acol0])     = ldb8(&X[xrow + k0 + acol0]);
        *reinterpret_cast<bf16x8*>(&As[arow][acol0 + 8]) = ldb8(&X[xrow + k0 + acol0 + 8]);
        *reinterpret_cast<bf16x8*>(&Bs[arow][acol0])     = ldb8(&Wt[wrow + k0 + acol0]);
        *reinterpret_cast<bf16x8*>(&Bs[arow][acol0 + 8]) = ldb8(&Wt[wrow + k0 + acol0 + 8]);
        __syncthreads();

        bf16x8 am[4], bn[4];
#pragma unroll
        for (int mi = 0; mi < 4; ++mi) am[mi] = ldb8(&As[wr * 64 + mi * 16 + c][g * 8]);
#pragma unroll
        for (int ni = 0; ni < 4; ++ni) bn[ni] = ldb8(&Bs[wc * 64 + ni * 16 + c][g * 8]);
#pragma unroll
        for (int mi = 0; mi < 4; ++mi)
#pragma unroll
            for (int ni = 0; ni < 4; ++ni)
                acc[mi][ni] = mfma16(am[mi], bn[ni], acc[mi][ni]);
    }

#pragma unroll
    for (int mi = 0; mi < 4; ++mi) {
        const int mbase = tm * 128 + wr * 64 + mi * 16 + g * 4;
#pragma unroll
        for (int ni = 0; ni < 4; ++ni) {
            const int n = tn * 128 + wc * 64 + ni * 16 + c;
#pragma unroll
            for (int r = 0; r < 4; ++r) {
                const int mm = mbase + r;
                float v = acc[mi][ni][r];
                if (MODE == 0) {
                    const float* bp = (n < 1024) ? bias0 : (n < 2048) ? bias1 : bias2;
                    const int nn = n & 1023;
                    v += bp[nn];
                    const int b = mm >> 11, s = mm & 2047;
                    const int h = nn >> 6, hd = nn & 63;
                    const size_t bh = (size_t)(b * H_ + h);
                    const __hip_bfloat16 bvv = __float2bfloat16(v);
                    if (n < 2048) {
                        __hip_bfloat16* dst = (n < 1024) ? Yq : Yk;
                        dst[(bh * S_ + s) * HD_ + hd] = bvv;
                    } else {
                        Yv[(bh * HD_ + hd) * S_ + s] = bvv;
                    }
                } else {
                    Yo[(size_t)mm * N + n] = v + bias0[n];
                }
            }
        }
    }
}

// ---------------- fused attention, k-split across waves ----------------
// grid: B*H*(S/16) blocks of 4 waves. Block owns 16 q-rows; wave w owns
// k in [w*512, (w+1)*512). Two passes over the k-range (recompute QK^T),
// probs staged bf16 in per-wave LDS then written as coalesced float4.
__global__ __launch_bounds__(256) void attn_kernel(
    const __hip_bfloat16* __restrict__ Qh, const __hip_bfloat16* __restrict__ Kh,
    const __hip_bfloat16* __restrict__ Vt, const float* __restrict__ mask,
    float* __restrict__ probs, __hip_bfloat16* __restrict__ ctx) {
    union SMem {
        __hip_bfloat16 Pb[4][16][72];  // per-wave P stage (bf16), 9216 B
        float Cred[4][16][68];         // ctx partial reduce, 17408 B
    };
    __shared__ SMem sm;
    __shared__ float sred[4][16];

    const int blk = blockIdx.x;
    const int qt = blk & 127;        // S/16
    const int bh = blk >> 7;
    const int b = bh >> 4, h = bh & 15;
    const int t = threadIdx.x;
    const int w = t >> 6, l = t & 63, g = l >> 4, c = l & 15;
    const int q0 = qt * 16;
    const int kbase = w * 512;

    const __hip_bfloat16* Qb = Qh + (size_t)bh * S_ * HD_;
    const __hip_bfloat16* Kb = Kh + (size_t)bh * S_ * HD_;
    const __hip_bfloat16* Vb = Vt + (size_t)bh * HD_ * S_;
    const float* mrow = mask + (size_t)b * S_;

    const bf16x8 aq0 = ldb8(&Qb[(q0 + c) * HD_ + g * 8]);
    const bf16x8 aq1 = ldb8(&Qb[(q0 + c) * HD_ + 32 + g * 8]);

    // ---- pass 1: partial denominators over this wave's k-range ----
    float lsum[4] = {0.f, 0.f, 0.f, 0.f};
#pragma unroll 2
    for (int kt = 0; kt < 32; ++kt) {
        const int k0 = kbase + kt * 16;
        const bf16x8 bk0 = ldb8(&Kb[(k0 + c) * HD_ + g * 8]);
        const bf16x8 bk1 = ldb8(&Kb[(k0 + c) * HD_ + 32 + g * 8]);
        f32x4 acc = {};
        acc = mfma16(aq0, bk0, acc);
        acc = mfma16(aq1, bk1, acc);
        const float mk = mrow[k0 + c];
#pragma unroll
        for (int r = 0; r < 4; ++r) lsum[r] += __expf(acc[r] * 0.125f + mk);
    }
#pragma unroll
    for (int r = 0; r < 4; ++r) {
#pragma unroll
        for (int msk = 1; msk < 16; msk <<= 1) lsum[r] += __shfl_xor(lsum[r], msk);
    }
    if (c == 0) {
#pragma unroll
        for (int r = 0; r < 4; ++r) sred[w][g * 4 + r] = lsum[r];
    }
    __syncthreads();
    float inv[4];
#pragma unroll
    for (int r = 0; r < 4; ++r)
        inv[r] = 1.0f / (sred[0][g * 4 + r] + sred[1][g * 4 + r] +
                         sred[2][g * 4 + r] + sred[3][g * 4 + r]);

    // ---- pass 2: probs (coalesced) + partial PV over this wave's k-range ----
    f32x4 cacc[4] = {};
    for (int ch = 0; ch < 8; ++ch) {
        const int k0 = kbase + ch * 64;
#pragma unroll
        for (int sub = 0; sub < 4; ++sub) {
            const int kk = k0 + sub * 16;
            const bf16x8 bk0 = ldb8(&Kb[(kk + c) * HD_ + g * 8]);
            const bf16x8 bk1 = ldb8(&Kb[(kk + c) * HD_ + 32 + g * 8]);
            f32x4 acc = {};
            acc = mfma16(aq0, bk0, acc);
            acc = mfma16(aq1, bk1, acc);
            const float mk = mrow[kk + c];
#pragma unroll
            for (int r = 0; r < 4; ++r) {
                const float p = __expf(acc[r] * 0.125f + mk) * inv[r];
                sm.Pb[w][g * 4 + r][sub * 16 + c] = __float2bfloat16(p);
            }
        }
        // coalesced probs store: 16 rows x 64 cols fp32, 256B/row segments
#pragma unroll
        for (int rr = 0; rr < 4; ++rr) {
            const int row = rr * 4 + g;
            const bf16x4 pv = *reinterpret_cast<const bf16x4*>(&sm.Pb[w][row][c * 4]);
            float4 o;
            o.x = bf2f(pv[0]); o.y = bf2f(pv[1]); o.z = bf2f(pv[2]); o.w = bf2f(pv[3]);
            *reinterpret_cast<float4*>(
                &probs[((size_t)bh * S_ + q0 + row) * S_ + k0 + c * 4]) = o;
        }
        // PV: A-fragment straight from LDS
#pragma unroll
        for (int half = 0; half < 2; ++half) {
            const bf16x8 ap = ldb8(&sm.Pb[w][c][half * 32 + g * 8]);
            const int kk = k0 + half * 32;
#pragma unroll
            for (int n = 0; n < 4; ++n) {
                const bf16x8 bv = ldb8(&Vb[(n * 16 + c) * S_ + kk + g * 8]);
                cacc[n] = mfma16(ap, bv, cacc[n]);
            }
        }
    }

    // ---- cross-wave PV reduce (reuses union'd LDS) ----
    __syncthreads();
#pragma unroll
    for (int n = 0; n < 4; ++n)
#pragma unroll
        for (int r = 0; r < 4; ++r)
            sm.Cred[w][g * 4 + r][n * 16 + c] = cacc[n][r];
    __syncthreads();

    const int row = t >> 4, col4 = (t & 15) * 4;
    float4 s0 = *reinterpret_cast<const float4*>(&sm.Cred[0][row][col4]);
    float4 s1 = *reinterpret_cast<const float4*>(&sm.Cred[1][row][col4]);
    float4 s2 = *reinterpret_cast<const float4*>(&sm.Cred[2][row][col4]);
    float4 s3 = *reinterpret_cast<const float4*>(&sm.Cred[3][row][col4]);
    union { __hip_bfloat16 hh[4]; ushort4 u; } ov;
    ov.hh[0] = __float2bfloat16(s0.x + s1.x + s2.x + s3.x);
    ov.hh[1] = __float2bfloat16(s0.y + s1.y + s2.y + s3.y);
    ov.hh[2] = __float2bfloat16(s0.z + s1.z + s2.z + s3.z);
    ov.hh[3] = __float2bfloat16(s0.w + s1.w + s2.w + s3.w);
    *reinterpret_cast<ushort4*>(
        &ctx[((size_t)b * S_ + q0 + row) * D_ + h * HD_ + col4]) = ov.u;
}

// ---------------- launch ----------------
extern "C" void kernel_launch(void* const* d_in, const int* in_sizes, int n_in,
                              void* d_out, int out_size, void* d_ws, size_t ws_size,
                              hipStream_t stream) {
    const float* hs   = (const float*)d_in[0];
    const float* mask = (const float*)d_in[1];
    const float* Wq   = (const float*)d_in[2];
    const float* bq   = (const float*)d_in[3];
    const float* Wk   = (const float*)d_in[4];
    const float* bk   = (const float*)d_in[5];
    const float* Wv   = (const float*)d_in[6];
    const float* bv   = (const float*)d_in[7];
    const float* Wo   = (const float*)d_in[8];
    const float* bo   = (const float*)d_in[9];

    float* out   = (float*)d_out;
    float* probs = out + (size_t)B_ * S_ * D_;

    const size_t MD = (size_t)B_ * S_ * D_;  // 4096*1024
    __hip_bfloat16* hsb   = (__hip_bfloat16*)d_ws;
    __hip_bfloat16* wqkvb = hsb + MD;
    __hip_bfloat16* wob   = wqkvb + 3u * 1024u * 1024u;
    __hip_bfloat16* Qh    = wob + (size_t)1024 * 1024;
    __hip_bfloat16* Kh    = Qh + MD;
    __hip_bfloat16* Vt    = Kh + MD;
    __hip_bfloat16* ctxb  = Vt + MD;

    conv_kernel<<<4096, 256, 0, stream>>>(hs, hsb, (int)(MD / 4));
    conv_kernel<<<1024, 256, 0, stream>>>(Wq, wqkvb, 262144);
    conv_kernel<<<1024, 256, 0, stream>>>(Wk, wqkvb + 1048576, 262144);
    conv_kernel<<<1024, 256, 0, stream>>>(Wv, wqkvb + 2097152, 262144);
    conv_kernel<<<1024, 256, 0, stream>>>(Wo, wob, 262144);

    gemm_bt<0><<<32 * 24, 256, 0, stream>>>(hsb, wqkvb, bq, bk, bv,
                                            Qh, Kh, Vt, nullptr, 4096, 3072, 1024);

    attn_kernel<<<B_ * H_ * (S_ / 16), 256, 0, stream>>>(Qh, Kh, Vt, mask, probs, ctxb);

    gemm_bt<1><<<32 * 8, 256, 0, stream>>>(ctxb, wob, bo, nullptr, nullptr,
                                           nullptr, nullptr, nullptr, out, 4096, 1024, 1024);
}